// Round 6
// baseline (815.954 us; speedup 1.0000x reference)
//
#include <hip/hip_runtime.h>
#include <math.h>

#define NN 20000   // nodes
#define NE 320000  // edges (without self-loops)
#define TT 8       // timesteps
#define D1 256     // H*F layer-1 width
#define CD 32      // layer-2 width == LSTM hidden

// ---------------- CSR build (once per launch; edges identical across t) ----------------

__global__ __launch_bounds__(256) void k_deg(const int* __restrict__ dst, int* __restrict__ deg) {
  int e = blockIdx.x * 256 + threadIdx.x;
  if (e < NE) atomicAdd(&deg[dst[e]], 1);
}

__global__ __launch_bounds__(1024) void k_scan(const int* __restrict__ deg,
                                               int* __restrict__ rowptr, int* __restrict__ fill) {
  __shared__ int sd[1024];
  __shared__ int carry_s;
  int tid = threadIdx.x;
  if (tid == 0) { carry_s = 0; rowptr[0] = 0; }
  __syncthreads();
  for (int base = 0; base < NN; base += 1024) {
    int i = base + tid;
    int v = (i < NN) ? deg[i] : 0;
    sd[tid] = v;
    __syncthreads();
    for (int off = 1; off < 1024; off <<= 1) {
      int t = (tid >= off) ? sd[tid - off] : 0;
      __syncthreads();
      sd[tid] += t;
      __syncthreads();
    }
    int incl = sd[tid];
    int carry = carry_s;
    if (i < NN) { rowptr[i + 1] = carry + incl; fill[i] = carry + incl - v; }
    __syncthreads();
    if (tid == 1023) carry_s = carry + sd[1023];
    __syncthreads();
  }
}

__global__ __launch_bounds__(256) void k_fill(const int* __restrict__ src, const int* __restrict__ dst,
                                              int* __restrict__ fill, int* __restrict__ csr,
                                              int* __restrict__ dstIdx) {
  int e = blockIdx.x * 256 + threadIdx.x;
  if (e < NE) {
    int d = dst[e];
    int pos = atomicAdd(&fill[d], 1);
    csr[pos] = src[e];
    dstIdx[pos] = d;
  }
}

// ---------------- one-time: folded attention vectors + weight transposes --------------------

__global__ __launch_bounds__(256) void k_prew(const float* __restrict__ W1,
    const float* __restrict__ as1, const float* __restrict__ ad1,
    const float* __restrict__ W2,
    float* __restrict__ wsrc, float* __restrict__ wdst,
    float* __restrict__ W1T, float* __restrict__ W2T) {
  int tid = threadIdx.x;
  int k = tid >> 3, h = tid & 7;
  float s = 0.f, d = 0.f;
  #pragma unroll
  for (int f = 0; f < 32; ++f) {
    float wv = W1[k * D1 + h * 32 + f];
    s = fmaf(wv, as1[h * 32 + f], s);
    d = fmaf(wv, ad1[h * 32 + f], d);
  }
  wsrc[k * 8 + h] = s;
  wdst[k * 8 + h] = d;
  for (int i = tid; i < D1 * 32; i += 256) {
    int j = i >> 5, kk = i & 31;
    W1T[i] = W1[kk * D1 + j];          // W1T[j*32+kk]
  }
  for (int i = tid; i < 32 * D1; i += 256) {
    int f = i >> 8, kk = i & 255;
    W2T[i] = W2[kk * CD + f];          // W2T[f*256+kk]
  }
}

// ---------------- logits for all t: als/ald = x @ w~ ; t = blockIdx.x & 7 -------------------

__global__ __launch_bounds__(256) void k_logits8(const float* __restrict__ x,
    const float* __restrict__ wsrc, const float* __restrict__ wdst,
    float* __restrict__ als, float* __restrict__ ald) {
  __shared__ float xs[32 * 33];
  __shared__ float wsr[256], wdr[256];
  int tid = threadIdx.x;
  int t = blockIdx.x & 7;
  int n0 = (blockIdx.x >> 3) * 32;
  const float* xt = x + (size_t)t * NN * 32;
  int nl = tid >> 3, h = tid & 7;
  for (int i = tid; i < 1024; i += 256) {
    int g = i >> 5, k = i & 31;
    xs[g * 33 + k] = xt[n0 * 32 + i];
  }
  wsr[tid] = wsrc[tid];
  wdr[tid] = wdst[tid];
  __syncthreads();
  const float* xr = xs + nl * 33;
  float as = 0.f, ad = 0.f;
  #pragma unroll
  for (int k = 0; k < 32; ++k) {
    float xv = xr[k];
    as = fmaf(xv, wsr[k * 8 + h], as);
    ad = fmaf(xv, wdr[k * 8 + h], ad);
  }
  als[(size_t)t * NN * 8 + n0 * 8 + tid] = as;
  ald[(size_t)t * NN * 8 + n0 * 8 + tid] = ad;
}

// ---------------- edge-parallel exp weights, layer 1: ew1[t][idx][h] ------------------------
// thread per (CSR slot, head); latency of the als/ald gathers hidden by 20M-thread TLP.

__global__ __launch_bounds__(256) void k_ew1(const int* __restrict__ csr,
    const int* __restrict__ dstIdx,
    const float* __restrict__ als, const float* __restrict__ ald,
    float* __restrict__ ew1) {
  int t = blockIdx.y;
  int i = blockIdx.x * 256 + threadIdx.x;   // i = idx*8 + h
  int idx = i >> 3, h = i & 7;
  int s = csr[idx], d = dstIdx[idx];
  const float* alst = als + (size_t)t * NN * 8;
  const float* aldt = ald + (size_t)t * NN * 8;
  float a = alst[s * 8 + h] + aldt[d * 8 + h];
  a = a > 0.f ? a : 0.2f * a;
  ew1[(size_t)t * NE * 8 + i] = __expf(a);
}

// ---------------- edge-parallel exp weights, layer 2: ew2[t][idx] ---------------------------

__global__ __launch_bounds__(256) void k_ew2(const int* __restrict__ csr,
    const int* __restrict__ dstIdx,
    const float* __restrict__ al2s, const float* __restrict__ al2d,
    float* __restrict__ ew2) {
  int t = blockIdx.y;
  int idx = blockIdx.x * 256 + threadIdx.x;
  int s = csr[idx], d = dstIdx[idx];
  float a = al2s[(size_t)t * NN + s] + al2d[(size_t)t * NN + d];
  a = a > 0.f ? a : 0.2f * a;
  ew2[(size_t)t * NE + idx] = __expf(a);
}

// ---------------- fused layer-1 gather + post1 GEMM + layer-2 GEMM, all t -------------------
// block: 4 nodes (one per wave). Phase 1: only dependent pair is csr[idx] -> x4 gather;
// ew1 is a sequential, csr-independent load. 8 gathers in flight (load-all-then-fma).

__global__ __launch_bounds__(256, 4) void k_fused8(const float* __restrict__ x,
    const float* __restrict__ W1T, const float* __restrict__ b1,
    const float* __restrict__ W2T, const float* __restrict__ as2, const float* __restrict__ ad2,
    const float* __restrict__ als, const float* __restrict__ ald,
    const float* __restrict__ ew1,
    const int* __restrict__ rowptr, const int* __restrict__ csr,
    float* __restrict__ h2, float* __restrict__ al2s, float* __restrict__ al2d) {
  __shared__ float aggs[4 * 256];
  __shared__ float dens[4 * 8];
  __shared__ float rels[4 * 256];
  __shared__ float part[4][4][32];
  int tid = threadIdx.x;
  int t = blockIdx.x & 7;
  int n0 = (blockIdx.x >> 3) * 4;
  const float* xt = x + (size_t)t * NN * 32;
  const float* alst = als + (size_t)t * NN * 8;
  const float* aldt = ald + (size_t)t * NN * 8;
  const float* ewt = ew1 + (size_t)t * NE * 8;

  // ---- phase 1: per-node gather in x-space
  int wv = tid >> 6, lane = tid & 63;
  int n = n0 + wv;
  int h = lane >> 3, fb = lane & 7;
  const float4* x4 = (const float4*)xt;
  float4 acc = make_float4(0.f, 0.f, 0.f, 0.f);
  float den = 0.f;
  int beg = rowptr[n], end = rowptr[n + 1];
  int idx = beg;
  for (; idx + 8 <= end; idx += 8) {
    int ss[8]; float ee[8]; float4 vv[8];
    #pragma unroll
    for (int u = 0; u < 8; ++u) ss[u] = csr[idx + u];
    #pragma unroll
    for (int u = 0; u < 8; ++u) ee[u] = ewt[(size_t)(idx + u) * 8 + h];
    #pragma unroll
    for (int u = 0; u < 8; ++u) vv[u] = x4[(size_t)ss[u] * 8 + fb];
    #pragma unroll
    for (int u = 0; u < 8; ++u) {
      acc.x = fmaf(ee[u], vv[u].x, acc.x);
      acc.y = fmaf(ee[u], vv[u].y, acc.y);
      acc.z = fmaf(ee[u], vv[u].z, acc.z);
      acc.w = fmaf(ee[u], vv[u].w, acc.w);
      den += ee[u];
    }
  }
  for (; idx < end; ++idx) {
    int s = csr[idx];
    float e = ewt[(size_t)idx * 8 + h];
    float4 v = x4[(size_t)s * 8 + fb];
    acc.x = fmaf(e, v.x, acc.x);
    acc.y = fmaf(e, v.y, acc.y);
    acc.z = fmaf(e, v.z, acc.z);
    acc.w = fmaf(e, v.w, acc.w);
    den += e;
  }
  {  // self-loop
    float a = alst[n * 8 + h] + aldt[n * 8 + h];
    a = a > 0.f ? a : 0.2f * a;
    float e = __expf(a);
    float4 v = x4[(size_t)n * 8 + fb];
    acc.x = fmaf(e, v.x, acc.x);
    acc.y = fmaf(e, v.y, acc.y);
    acc.z = fmaf(e, v.z, acc.z);
    acc.w = fmaf(e, v.w, acc.w);
    den += e;
  }
  *(float4*)(aggs + wv * 256 + h * 32 + fb * 4) = acc;
  if (fb == 0) dens[wv * 8 + h] = den;

  // weight columns into VGPRs (contiguous float4 from transposed layouts)
  int j = tid;
  float4 w1v[8];
  const float4* w1p = (const float4*)(W1T + j * 32);
  #pragma unroll
  for (int q8 = 0; q8 < 8; ++q8) w1v[q8] = w1p[q8];
  float bj = b1[j];
  int q = tid >> 5, f = tid & 31;
  float4 w2v[8];
  const float4* w2p = (const float4*)(W2T + f * 256 + q * 32);
  #pragma unroll
  for (int q8 = 0; q8 < 8; ++q8) w2v[q8] = w2p[q8];
  __syncthreads();

  // ---- phase 2: rel1 = relu(aggx @ W1_head / den + b1); b128 broadcast reads
  int hj = j >> 5;
  #pragma unroll
  for (int g = 0; g < 4; ++g) {
    const float4* ar4 = (const float4*)(aggs + g * 256 + hj * 32);
    float a = 0.f;
    #pragma unroll
    for (int k4 = 0; k4 < 8; ++k4) {
      float4 av = ar4[k4];
      a = fmaf(av.x, w1v[k4].x, fmaf(av.y, w1v[k4].y,
          fmaf(av.z, w1v[k4].z, fmaf(av.w, w1v[k4].w, a))));
    }
    float v = fmaf(a, 1.f / dens[g * 8 + hj], bj);
    rels[g * 256 + j] = fmaxf(v, 0.f);
  }
  __syncthreads();

  // ---- phase 3: h2 = rel1 @ W2 (k-split over q, reduce via shuffle + LDS)
  float accg[4];
  #pragma unroll
  for (int g = 0; g < 4; ++g) {
    const float4* r4 = (const float4*)(rels + g * 256 + q * 32);
    float a = 0.f;
    #pragma unroll
    for (int jj = 0; jj < 8; ++jj) {
      float4 a4 = r4[jj];
      a = fmaf(a4.x, w2v[jj].x, fmaf(a4.y, w2v[jj].y,
          fmaf(a4.z, w2v[jj].z, fmaf(a4.w, w2v[jj].w, a))));
    }
    a += __shfl_xor(a, 32, 64);
    accg[g] = a;
  }
  if ((tid & 32) == 0) {
    #pragma unroll
    for (int g = 0; g < 4; ++g) part[wv][g][f] = accg[g];
  }
  __syncthreads();
  if (tid < 128) {
    int g = tid >> 5, ff = tid & 31;
    float v = part[0][g][ff] + part[1][g][ff] + part[2][g][ff] + part[3][g][ff];
    int nn = n0 + g;
    h2[(size_t)t * NN * CD + nn * CD + ff] = v;
    float vs = v * as2[ff], vd = v * ad2[ff];
    #pragma unroll
    for (int m = 1; m < 32; m <<= 1) {
      vs += __shfl_xor(vs, m, 64);
      vd += __shfl_xor(vd, m, 64);
    }
    if (ff == 0) {
      al2s[(size_t)t * NN + nn] = vs;
      al2d[(size_t)t * NN + nn] = vd;
    }
  }
}

// ---------------- GAT layer 2 aggregation, all t: 32 threads per node, 8-deep gather --------

__global__ __launch_bounds__(256) void k_agg2_8(const float* __restrict__ h2,
    const float* __restrict__ al2s, const float* __restrict__ al2d,
    const float* __restrict__ ew2,
    const int* __restrict__ rowptr, const int* __restrict__ csr,
    const float* __restrict__ b2, float* __restrict__ out) {
  int tid = threadIdx.x;
  int t = blockIdx.x & 7;
  int hw = tid >> 5, f = tid & 31;
  int n = (blockIdx.x >> 3) * 8 + hw;
  const float* h2t = h2 + (size_t)t * NN * CD;
  const float* ewt = ew2 + (size_t)t * NE;
  float acc = 0.f, den = 0.f;
  int beg = rowptr[n], end = rowptr[n + 1];
  int idx = beg;
  for (; idx + 8 <= end; idx += 8) {
    int ss[8]; float ee[8]; float vv[8];
    #pragma unroll
    for (int u = 0; u < 8; ++u) ss[u] = csr[idx + u];
    #pragma unroll
    for (int u = 0; u < 8; ++u) ee[u] = ewt[idx + u];
    #pragma unroll
    for (int u = 0; u < 8; ++u) vv[u] = h2t[(size_t)ss[u] * CD + f];
    #pragma unroll
    for (int u = 0; u < 8; ++u) {
      acc = fmaf(ee[u], vv[u], acc);
      den += ee[u];
    }
  }
  for (; idx < end; ++idx) {
    int s = csr[idx];
    float e = ewt[idx];
    acc = fmaf(e, h2t[(size_t)s * CD + f], acc);
    den += e;
  }
  {  // self-loop
    float a = al2s[(size_t)t * NN + n] + al2d[(size_t)t * NN + n];
    a = a > 0.f ? a : 0.2f * a;
    float e = __expf(a);
    acc = fmaf(e, h2t[(size_t)n * CD + f], acc);
    den += e;
  }
  out[(size_t)t * NN * CD + (size_t)n * CD + f] = acc / den + b2[f];
}

// ---------------- LSTM, all t in one kernel: weights in VGPRs, h/c in LDS ------------------

__global__ __launch_bounds__(256) void k_lstm_all(const float* __restrict__ agg2o,
    const float* __restrict__ w_ih, const float* __restrict__ w_hh,
    const float* __restrict__ b_ih, const float* __restrict__ b_hh,
    float* __restrict__ out) {
  __shared__ float xs[16 * 32], hs[16 * 32], cs[16 * 32], pre[16 * 128];
  int tid = threadIdx.x;
  int slot = tid >> 7;
  int r = tid & 127;
  float4 wi[8], wh[8];
  const float4* wi4 = (const float4*)(w_ih + r * 32);
  const float4* wh4 = (const float4*)(w_hh + r * 32);
  #pragma unroll
  for (int q = 0; q < 8; ++q) { wi[q] = wi4[q]; wh[q] = wh4[q]; }
  float bias = b_ih[r] + b_hh[r];
  int base = blockIdx.x * 16;
  for (int i = tid; i < 512; i += 256) { hs[i] = 0.f; cs[i] = 0.f; }
  for (int t = 0; t < TT; ++t) {
    for (int i = tid; i < 512; i += 256) xs[i] = agg2o[(size_t)t * NN * 32 + base * 32 + i];
    __syncthreads();
    #pragma unroll
    for (int g = 0; g < 8; ++g) {
      int nl = slot * 8 + g;
      const float4* xv4 = (const float4*)(xs + nl * 32);
      const float4* hv4 = (const float4*)(hs + nl * 32);
      float acc = bias;
      #pragma unroll
      for (int q = 0; q < 8; ++q) {
        float4 a = xv4[q], b = hv4[q];
        acc = fmaf(a.x, wi[q].x, acc);
        acc = fmaf(a.y, wi[q].y, acc);
        acc = fmaf(a.z, wi[q].z, acc);
        acc = fmaf(a.w, wi[q].w, acc);
        acc = fmaf(b.x, wh[q].x, acc);
        acc = fmaf(b.y, wh[q].y, acc);
        acc = fmaf(b.z, wh[q].z, acc);
        acc = fmaf(b.w, wh[q].w, acc);
      }
      pre[nl * 128 + r] = acc;
    }
    __syncthreads();
    for (int i = tid; i < 512; i += 256) {
      int nl = i >> 5, k = i & 31;
      float ai = pre[nl * 128 + k];
      float af = pre[nl * 128 + 32 + k];
      float ag = pre[nl * 128 + 64 + k];
      float ao = pre[nl * 128 + 96 + k];
      float ii = 1.f / (1.f + __expf(-ai));
      float ff = 1.f / (1.f + __expf(-af));
      float gg = tanhf(ag);
      float oo = 1.f / (1.f + __expf(-ao));
      float cn = fmaf(ff, cs[i], ii * gg);
      float hn = oo * tanhf(cn);
      cs[i] = cn; hs[i] = hn;
      out[(size_t)t * NN * 32 + base * 32 + i] = hn;
    }
  }
}

// ---------------- softmax over nodes, coalesced two-pass ----------------

__global__ __launch_bounds__(256) void k_sm_sum(const float* __restrict__ out, float* __restrict__ sums) {
  int t = blockIdx.y;
  const float4* b4 = (const float4*)(out + ((size_t)t * NN + blockIdx.x * 800) * CD);
  int tid = threadIdx.x;
  float4 s4 = make_float4(0.f, 0.f, 0.f, 0.f);
  for (int i = tid; i < 6400; i += 256) {
    float4 v = b4[i];
    s4.x += __expf(v.x); s4.y += __expf(v.y);
    s4.z += __expf(v.z); s4.w += __expf(v.w);
  }
  __shared__ float4 red[256];
  red[tid] = s4;
  __syncthreads();
  for (int off = 128; off >= 8; off >>= 1) {
    if (tid < off) {
      float4 o = red[tid + off];
      red[tid].x += o.x; red[tid].y += o.y; red[tid].z += o.z; red[tid].w += o.w;
    }
    __syncthreads();
  }
  if (tid < 8) {
    float4 v = red[tid];
    int c0 = tid * 4;
    atomicAdd(&sums[t * CD + c0 + 0], v.x);
    atomicAdd(&sums[t * CD + c0 + 1], v.y);
    atomicAdd(&sums[t * CD + c0 + 2], v.z);
    atomicAdd(&sums[t * CD + c0 + 3], v.w);
  }
}

__global__ __launch_bounds__(256) void k_sm_scale(float* __restrict__ out, const float* __restrict__ sums) {
  int t = blockIdx.y;
  __shared__ float inv[CD];
  int tid = threadIdx.x;
  if (tid < CD) inv[tid] = 1.f / sums[t * CD + tid];
  __syncthreads();
  float4* b4 = (float4*)(out + ((size_t)t * NN + blockIdx.x * 800) * CD);
  for (int i = tid; i < 6400; i += 256) {
    float4 v = b4[i];
    int c0 = (4 * i) & 31;
    v.x = __expf(v.x) * inv[c0];
    v.y = __expf(v.y) * inv[c0 + 1];
    v.z = __expf(v.z) * inv[c0 + 2];
    v.w = __expf(v.w) * inv[c0 + 3];
    b4[i] = v;
  }
}

// ---------------- launch ----------------

extern "C" void kernel_launch(void* const* d_in, const int* in_sizes, int n_in,
                              void* d_out, int out_size, void* d_ws, size_t ws_size,
                              hipStream_t stream) {
  const float* x   = (const float*)d_in[0];
  const float* W1  = (const float*)d_in[1];
  const float* as1 = (const float*)d_in[2];
  const float* ad1 = (const float*)d_in[3];
  const float* b1  = (const float*)d_in[4];
  const float* W2  = (const float*)d_in[5];
  const float* as2 = (const float*)d_in[6];
  const float* ad2 = (const float*)d_in[7];
  const float* b2  = (const float*)d_in[8];
  const float* wih = (const float*)d_in[9];
  const float* whh = (const float*)d_in[10];
  const float* bih = (const float*)d_in[11];
  const float* bhh = (const float*)d_in[12];
  const int*   ei  = (const int*)d_in[13];
  const int* srcp = ei;
  const int* dstp = ei + NE;
  float* out = (float*)d_out;

  float* ws = (float*)d_ws;
  float* al1s  = ws;  ws += (size_t)TT * NN * 8;
  float* al1d  = ws;  ws += (size_t)TT * NN * 8;
  float* h2    = ws;  ws += (size_t)TT * NN * CD;
  float* al2s  = ws;  ws += (size_t)TT * NN;
  float* al2d  = ws;  ws += (size_t)TT * NN;
  float* agg2o = ws;  ws += (size_t)TT * NN * CD;
  float* ew1   = ws;  ws += (size_t)TT * NE * 8;
  float* ew2   = ws;  ws += (size_t)TT * NE;
  float* sums  = ws;  ws += TT * CD;
  float* wsrc  = ws;  ws += 256;
  float* wdst  = ws;  ws += 256;
  float* W1T   = ws;  ws += D1 * 32;
  float* W2T   = ws;  ws += 32 * D1;
  int* rowptr = (int*)ws;
  int* fill   = rowptr + NN + 1;
  int* csr    = fill + NN;
  int* deg    = csr + NE;
  int* dstIdx = deg + NN;

  hipMemsetAsync(sums, 0, TT * CD * sizeof(float), stream);
  hipMemsetAsync(deg, 0, NN * sizeof(int), stream);

  k_deg<<<(NE + 255) / 256, 256, 0, stream>>>(dstp, deg);
  k_scan<<<1, 1024, 0, stream>>>(deg, rowptr, fill);
  k_fill<<<(NE + 255) / 256, 256, 0, stream>>>(srcp, dstp, fill, csr, dstIdx);
  k_prew<<<1, 256, 0, stream>>>(W1, as1, ad1, W2, wsrc, wdst, W1T, W2T);

  k_logits8<<<(NN / 32) * TT, 256, 0, stream>>>(x, wsrc, wdst, al1s, al1d);
  k_ew1<<<dim3(NE * 8 / 256, TT), 256, 0, stream>>>(csr, dstIdx, al1s, al1d, ew1);
  k_fused8<<<(NN / 4) * TT, 256, 0, stream>>>(x, W1T, b1, W2T, as2, ad2,
                                              al1s, al1d, ew1, rowptr, csr, h2, al2s, al2d);
  k_ew2<<<dim3(NE / 256, TT), 256, 0, stream>>>(csr, dstIdx, al2s, al2d, ew2);
  k_agg2_8<<<(NN / 8) * TT, 256, 0, stream>>>(h2, al2s, al2d, ew2, rowptr, csr, b2, agg2o);
  k_lstm_all<<<NN / 16, 256, 0, stream>>>(agg2o, wih, whh, bih, bhh, out);

  k_sm_sum<<<dim3(25, TT), 256, 0, stream>>>(out, sums);
  k_sm_scale<<<dim3(25, TT), 256, 0, stream>>>(out, sums);
}

// Round 7
// 673.230 us; speedup vs baseline: 1.2120x; 1.2120x over previous
//
#include <hip/hip_runtime.h>
#include <math.h>

#define NN 20000   // nodes
#define NE 320000  // edges (without self-loops)
#define TT 8       // timesteps
#define D1 256     // H*F layer-1 width
#define CD 32      // layer-2 width == LSTM hidden
#define PG1 1024   // persistent grid, k_fused8 (4 blocks/CU)
#define PG2 2048   // persistent grid, k_agg2_8 (8 blocks/CU)

// ---------------- CSR build (once per launch; edges identical across t) ----------------

__global__ __launch_bounds__(256) void k_deg(const int* __restrict__ dst, int* __restrict__ deg) {
  int e = blockIdx.x * 256 + threadIdx.x;
  if (e < NE) atomicAdd(&deg[dst[e]], 1);
}

__global__ __launch_bounds__(1024) void k_scan(const int* __restrict__ deg,
                                               int* __restrict__ rowptr, int* __restrict__ fill) {
  __shared__ int sd[1024];
  __shared__ int carry_s;
  int tid = threadIdx.x;
  if (tid == 0) { carry_s = 0; rowptr[0] = 0; }
  __syncthreads();
  for (int base = 0; base < NN; base += 1024) {
    int i = base + tid;
    int v = (i < NN) ? deg[i] : 0;
    sd[tid] = v;
    __syncthreads();
    for (int off = 1; off < 1024; off <<= 1) {
      int t = (tid >= off) ? sd[tid - off] : 0;
      __syncthreads();
      sd[tid] += t;
      __syncthreads();
    }
    int incl = sd[tid];
    int carry = carry_s;
    if (i < NN) { rowptr[i + 1] = carry + incl; fill[i] = carry + incl - v; }
    __syncthreads();
    if (tid == 1023) carry_s = carry + sd[1023];
    __syncthreads();
  }
}

__global__ __launch_bounds__(256) void k_fill(const int* __restrict__ src, const int* __restrict__ dst,
                                              int* __restrict__ fill, int* __restrict__ csr) {
  int e = blockIdx.x * 256 + threadIdx.x;
  if (e < NE) {
    int pos = atomicAdd(&fill[dst[e]], 1);
    csr[pos] = src[e];
  }
}

// ---------------- one-time: folded attention vectors + weight transposes --------------------

__global__ __launch_bounds__(256) void k_prew(const float* __restrict__ W1,
    const float* __restrict__ as1, const float* __restrict__ ad1,
    const float* __restrict__ W2,
    float* __restrict__ wsrc, float* __restrict__ wdst,
    float* __restrict__ W1T, float* __restrict__ W2T) {
  int tid = threadIdx.x;
  int k = tid >> 3, h = tid & 7;
  float s = 0.f, d = 0.f;
  #pragma unroll
  for (int f = 0; f < 32; ++f) {
    float wv = W1[k * D1 + h * 32 + f];
    s = fmaf(wv, as1[h * 32 + f], s);
    d = fmaf(wv, ad1[h * 32 + f], d);
  }
  wsrc[k * 8 + h] = s;
  wdst[k * 8 + h] = d;
  for (int i = tid; i < D1 * 32; i += 256) {
    int j = i >> 5, kk = i & 31;
    W1T[i] = W1[kk * D1 + j];          // W1T[j*32+kk]
  }
  for (int i = tid; i < 32 * D1; i += 256) {
    int f = i >> 8, kk = i & 255;
    W2T[i] = W2[kk * CD + f];          // W2T[f*256+kk]
  }
}

// ---------------- logits for all t: als/ald = x @ w~ ; t = blockIdx.x & 7 -------------------

__global__ __launch_bounds__(256) void k_logits8(const float* __restrict__ x,
    const float* __restrict__ wsrc, const float* __restrict__ wdst,
    float* __restrict__ als, float* __restrict__ ald) {
  __shared__ float xs[32 * 33];
  __shared__ float wsr[256], wdr[256];
  int tid = threadIdx.x;
  int t = blockIdx.x & 7;
  int n0 = (blockIdx.x >> 3) * 32;
  const float* xt = x + (size_t)t * NN * 32;
  int nl = tid >> 3, h = tid & 7;
  for (int i = tid; i < 1024; i += 256) {
    int g = i >> 5, k = i & 31;
    xs[g * 33 + k] = xt[n0 * 32 + i];
  }
  wsr[tid] = wsrc[tid];
  wdr[tid] = wdst[tid];
  __syncthreads();
  const float* xr = xs + nl * 33;
  float as = 0.f, ad = 0.f;
  #pragma unroll
  for (int k = 0; k < 32; ++k) {
    float xv = xr[k];
    as = fmaf(xv, wsr[k * 8 + h], as);
    ad = fmaf(xv, wdr[k * 8 + h], ad);
  }
  als[(size_t)t * NN * 8 + n0 * 8 + tid] = as;
  ald[(size_t)t * NN * 8 + n0 * 8 + tid] = ad;
}

// ---------------- fused layer-1 gather + post1 GEMM + layer-2 GEMM -------------------------
// PERSISTENT blocks: weights loaded once into VGPRs (pinned by asm barrier), then
// grid-stride over (t, node-pair) groups. 2 waves per node halve the gather chain.
// t = (blockIdx + it*PG1) & 7 is constant per block -> x_t stays in that XCD's L2.

__global__ __launch_bounds__(256, 4) void k_fused8(const float* __restrict__ x,
    const float* __restrict__ W1T, const float* __restrict__ b1,
    const float* __restrict__ W2T, const float* __restrict__ as2, const float* __restrict__ ad2,
    const float* __restrict__ als, const float* __restrict__ ald,
    const int* __restrict__ rowptr, const int* __restrict__ csr,
    float* __restrict__ h2, float* __restrict__ al2s, float* __restrict__ al2d) {
  __shared__ float aggp[4][256];   // per-wave partial gather
  __shared__ float denp[4][8];
  __shared__ float aggs[2][256];   // combined per node
  __shared__ float dens[2][8];
  __shared__ float rels[2][256];
  __shared__ float part[4][2][32];
  int tid = threadIdx.x;

  // weight columns into VGPRs, once per block; pinned across the loop
  int j = tid;
  float4 w1v[8];
  const float4* w1p = (const float4*)(W1T + j * 32);
  #pragma unroll
  for (int q8 = 0; q8 < 8; ++q8) w1v[q8] = w1p[q8];
  float bj = b1[j];
  int q = tid >> 5, f = tid & 31;
  float4 w2v[8];
  const float4* w2p = (const float4*)(W2T + f * 256 + q * 32);
  #pragma unroll
  for (int q8 = 0; q8 < 8; ++q8) w2v[q8] = w2p[q8];
  float as2f = as2[f], ad2f = ad2[f];
  asm volatile("" ::: "memory");   // keep weight loads above the loop (force into regs)

  int wv = tid >> 6, lane = tid & 63;
  int h = lane >> 3, fb = lane & 7;
  int l_wave = wv >> 1, half = wv & 1;

  const int NG = (NN / 2) * TT;    // 80000 (t, node-pair) groups
  for (int it = 0; it < (NG + PG1 - 1) / PG1; ++it) {
    int g = blockIdx.x + it * PG1;
    bool active = g < NG;
    int t = g & 7;
    int n0 = (g >> 3) * 2;
    const float* xt = x + (size_t)t * NN * 32;
    const float* alst = als + (size_t)t * NN * 8;
    const float* aldt = ald + (size_t)t * NN * 8;

    // ---- phase 1: gather in x-space; wave (l_wave, half) takes half the edge list
    if (active) {
      int n = n0 + l_wave;
      float ad = aldt[n * 8 + h];
      const float4* x4 = (const float4*)xt;
      float4 acc = make_float4(0.f, 0.f, 0.f, 0.f);
      float den = 0.f;
      int beg = rowptr[n], end = rowptr[n + 1];
      int mid = beg + ((end - beg + 1) >> 1);
      int lo = half ? mid : beg;
      int hi = half ? end : mid;
      int idx = lo;
      for (; idx + 2 <= hi; idx += 2) {
        int s0 = csr[idx], s1 = csr[idx + 1];
        float a0 = alst[s0 * 8 + h] + ad;
        float a1 = alst[s1 * 8 + h] + ad;
        float4 v0 = x4[(size_t)s0 * 8 + fb];
        float4 v1 = x4[(size_t)s1 * 8 + fb];
        a0 = a0 > 0.f ? a0 : 0.2f * a0;
        a1 = a1 > 0.f ? a1 : 0.2f * a1;
        float e0 = __expf(a0), e1 = __expf(a1);
        acc.x = fmaf(e1, v1.x, fmaf(e0, v0.x, acc.x));
        acc.y = fmaf(e1, v1.y, fmaf(e0, v0.y, acc.y));
        acc.z = fmaf(e1, v1.z, fmaf(e0, v0.z, acc.z));
        acc.w = fmaf(e1, v1.w, fmaf(e0, v0.w, acc.w));
        den += e0 + e1;
      }
      for (; idx < hi; ++idx) {
        int s = csr[idx];
        float a = alst[s * 8 + h] + ad;
        a = a > 0.f ? a : 0.2f * a;
        float e = __expf(a);
        float4 v = x4[(size_t)s * 8 + fb];
        acc.x = fmaf(e, v.x, acc.x);
        acc.y = fmaf(e, v.y, acc.y);
        acc.z = fmaf(e, v.z, acc.z);
        acc.w = fmaf(e, v.w, acc.w);
        den += e;
      }
      if (half) {  // self-loop
        float a = alst[n * 8 + h] + ad;
        a = a > 0.f ? a : 0.2f * a;
        float e = __expf(a);
        float4 v = x4[(size_t)n * 8 + fb];
        acc.x = fmaf(e, v.x, acc.x);
        acc.y = fmaf(e, v.y, acc.y);
        acc.z = fmaf(e, v.z, acc.z);
        acc.w = fmaf(e, v.w, acc.w);
        den += e;
      }
      *(float4*)(&aggp[wv][h * 32 + fb * 4]) = acc;
      if (fb == 0) denp[wv][h] = den;
    }
    __syncthreads();

    // ---- combine halves
    if (active) {
      #pragma unroll
      for (int l = 0; l < 2; ++l) aggs[l][j] = aggp[2 * l][j] + aggp[2 * l + 1][j];
      if (tid < 16) {
        int l = tid >> 3, hh = tid & 7;
        dens[l][hh] = denp[2 * l][hh] + denp[2 * l + 1][hh];
      }
    }
    __syncthreads();

    // ---- phase 2: rel1 = relu(agg @ W1_head / den + b1)
    if (active) {
      int hj = j >> 5;
      #pragma unroll
      for (int l = 0; l < 2; ++l) {
        const float4* ar4 = (const float4*)(&aggs[l][hj * 32]);
        float a = 0.f;
        #pragma unroll
        for (int k4 = 0; k4 < 8; ++k4) {
          float4 av = ar4[k4];
          a = fmaf(av.x, w1v[k4].x, fmaf(av.y, w1v[k4].y,
              fmaf(av.z, w1v[k4].z, fmaf(av.w, w1v[k4].w, a))));
        }
        float v = fmaf(a, 1.f / dens[l][hj], bj);
        rels[l][j] = fmaxf(v, 0.f);
      }
    }
    __syncthreads();

    // ---- phase 3: h2 = rel1 @ W2 (k-split over q, reduce via shuffle + LDS)
    if (active) {
      float accg[2];
      #pragma unroll
      for (int l = 0; l < 2; ++l) {
        const float4* r4 = (const float4*)(&rels[l][q * 32]);
        float a = 0.f;
        #pragma unroll
        for (int jj = 0; jj < 8; ++jj) {
          float4 a4 = r4[jj];
          a = fmaf(a4.x, w2v[jj].x, fmaf(a4.y, w2v[jj].y,
              fmaf(a4.z, w2v[jj].z, fmaf(a4.w, w2v[jj].w, a))));
        }
        a += __shfl_xor(a, 32, 64);
        accg[l] = a;
      }
      if ((tid & 32) == 0) {
        #pragma unroll
        for (int l = 0; l < 2; ++l) part[wv][l][f] = accg[l];
      }
    }
    __syncthreads();

    if (active && tid < 64) {
      int l = tid >> 5, ff = tid & 31;
      float v = part[0][l][ff] + part[1][l][ff] + part[2][l][ff] + part[3][l][ff];
      int nn = n0 + l;
      h2[((size_t)t * NN + nn) * CD + ff] = v;
      float vs = v * as2f, vd = v * ad2f;
      #pragma unroll
      for (int m = 1; m < 32; m <<= 1) {
        vs += __shfl_xor(vs, m, 64);
        vd += __shfl_xor(vd, m, 64);
      }
      if (ff == 0) {
        al2s[(size_t)t * NN + nn] = vs;
        al2d[(size_t)t * NN + nn] = vd;
      }
    }
    __syncthreads();
  }
}

// ---------------- GAT layer 2 aggregation: persistent, full wave per node, 2 edge slots -----

__global__ __launch_bounds__(256, 8) void k_agg2_8(const float* __restrict__ h2,
    const float* __restrict__ al2s, const float* __restrict__ al2d,
    const int* __restrict__ rowptr, const int* __restrict__ csr,
    const float* __restrict__ b2, float* __restrict__ out) {
  int tid = threadIdx.x;
  int wv = tid >> 6, lane = tid & 63;
  int slot = lane >> 5, f = lane & 31;
  float b2f = b2[f];
  const int NG = (NN / 4) * TT;    // 40000 groups of 4 nodes
  for (int it = 0; it < (NG + PG2 - 1) / PG2; ++it) {
    int g = blockIdx.x + it * PG2;
    if (g >= NG) break;            // no barriers in this kernel: plain break is safe
    int t = g & 7;
    int n = (g >> 3) * 4 + wv;
    const float* h2t = h2 + (size_t)t * NN * CD;
    const float* alst = al2s + (size_t)t * NN;
    float ad = al2d[(size_t)t * NN + n];
    float acc = 0.f, den = 0.f;
    int beg = rowptr[n], end = rowptr[n + 1];
    int mid = beg + ((end - beg + 1) >> 1);
    int lo = slot ? mid : beg;
    int hi = slot ? end : mid;
    int idx = lo;
    for (; idx + 2 <= hi; idx += 2) {
      int s0 = csr[idx], s1 = csr[idx + 1];
      float a0 = alst[s0] + ad;
      float a1 = alst[s1] + ad;
      float v0 = h2t[(size_t)s0 * CD + f];
      float v1 = h2t[(size_t)s1 * CD + f];
      a0 = a0 > 0.f ? a0 : 0.2f * a0;
      a1 = a1 > 0.f ? a1 : 0.2f * a1;
      float e0 = __expf(a0), e1 = __expf(a1);
      acc = fmaf(e1, v1, fmaf(e0, v0, acc));
      den += e0 + e1;
    }
    for (; idx < hi; ++idx) {
      int s = csr[idx];
      float a = alst[s] + ad;
      a = a > 0.f ? a : 0.2f * a;
      float e = __expf(a);
      acc = fmaf(e, h2t[(size_t)s * CD + f], acc);
      den += e;
    }
    if (slot) {  // self-loop
      float a = alst[n] + ad;
      a = a > 0.f ? a : 0.2f * a;
      float e = __expf(a);
      acc = fmaf(e, h2t[(size_t)n * CD + f], acc);
      den += e;
    }
    acc += __shfl_xor(acc, 32, 64);
    den += __shfl_xor(den, 32, 64);
    if (slot == 0) out[((size_t)t * NN + n) * CD + f] = acc / den + b2f;
  }
}

// ---------------- LSTM, all t in one kernel: weights in VGPRs, h/c in LDS ------------------

__global__ __launch_bounds__(256) void k_lstm_all(const float* __restrict__ agg2o,
    const float* __restrict__ w_ih, const float* __restrict__ w_hh,
    const float* __restrict__ b_ih, const float* __restrict__ b_hh,
    float* __restrict__ out) {
  __shared__ float xs[16 * 32], hs[16 * 32], cs[16 * 32], pre[16 * 128];
  int tid = threadIdx.x;
  int slot = tid >> 7;
  int r = tid & 127;
  float4 wi[8], wh[8];
  const float4* wi4 = (const float4*)(w_ih + r * 32);
  const float4* wh4 = (const float4*)(w_hh + r * 32);
  #pragma unroll
  for (int q = 0; q < 8; ++q) { wi[q] = wi4[q]; wh[q] = wh4[q]; }
  float bias = b_ih[r] + b_hh[r];
  int base = blockIdx.x * 16;
  for (int i = tid; i < 512; i += 256) { hs[i] = 0.f; cs[i] = 0.f; }
  for (int t = 0; t < TT; ++t) {
    for (int i = tid; i < 512; i += 256) xs[i] = agg2o[(size_t)t * NN * 32 + base * 32 + i];
    __syncthreads();
    #pragma unroll
    for (int g = 0; g < 8; ++g) {
      int nl = slot * 8 + g;
      const float4* xv4 = (const float4*)(xs + nl * 32);
      const float4* hv4 = (const float4*)(hs + nl * 32);
      float acc = bias;
      #pragma unroll
      for (int q = 0; q < 8; ++q) {
        float4 a = xv4[q], b = hv4[q];
        acc = fmaf(a.x, wi[q].x, acc);
        acc = fmaf(a.y, wi[q].y, acc);
        acc = fmaf(a.z, wi[q].z, acc);
        acc = fmaf(a.w, wi[q].w, acc);
        acc = fmaf(b.x, wh[q].x, acc);
        acc = fmaf(b.y, wh[q].y, acc);
        acc = fmaf(b.z, wh[q].z, acc);
        acc = fmaf(b.w, wh[q].w, acc);
      }
      pre[nl * 128 + r] = acc;
    }
    __syncthreads();
    for (int i = tid; i < 512; i += 256) {
      int nl = i >> 5, k = i & 31;
      float ai = pre[nl * 128 + k];
      float af = pre[nl * 128 + 32 + k];
      float ag = pre[nl * 128 + 64 + k];
      float ao = pre[nl * 128 + 96 + k];
      float ii = 1.f / (1.f + __expf(-ai));
      float ff = 1.f / (1.f + __expf(-af));
      float gg = tanhf(ag);
      float oo = 1.f / (1.f + __expf(-ao));
      float cn = fmaf(ff, cs[i], ii * gg);
      float hn = oo * tanhf(cn);
      cs[i] = cn; hs[i] = hn;
      out[(size_t)t * NN * 32 + base * 32 + i] = hn;
    }
  }
}

// ---------------- softmax over nodes, coalesced two-pass ----------------

__global__ __launch_bounds__(256) void k_sm_sum(const float* __restrict__ out, float* __restrict__ sums) {
  int t = blockIdx.y;
  const float4* b4 = (const float4*)(out + ((size_t)t * NN + blockIdx.x * 800) * CD);
  int tid = threadIdx.x;
  float4 s4 = make_float4(0.f, 0.f, 0.f, 0.f);
  for (int i = tid; i < 6400; i += 256) {
    float4 v = b4[i];
    s4.x += __expf(v.x); s4.y += __expf(v.y);
    s4.z += __expf(v.z); s4.w += __expf(v.w);
  }
  __shared__ float4 red[256];
  red[tid] = s4;
  __syncthreads();
  for (int off = 128; off >= 8; off >>= 1) {
    if (tid < off) {
      float4 o = red[tid + off];
      red[tid].x += o.x; red[tid].y += o.y; red[tid].z += o.z; red[tid].w += o.w;
    }
    __syncthreads();
  }
  if (tid < 8) {
    float4 v = red[tid];
    int c0 = tid * 4;
    atomicAdd(&sums[t * CD + c0 + 0], v.x);
    atomicAdd(&sums[t * CD + c0 + 1], v.y);
    atomicAdd(&sums[t * CD + c0 + 2], v.z);
    atomicAdd(&sums[t * CD + c0 + 3], v.w);
  }
}

__global__ __launch_bounds__(256) void k_sm_scale(float* __restrict__ out, const float* __restrict__ sums) {
  int t = blockIdx.y;
  __shared__ float inv[CD];
  int tid = threadIdx.x;
  if (tid < CD) inv[tid] = 1.f / sums[t * CD + tid];
  __syncthreads();
  float4* b4 = (float4*)(out + ((size_t)t * NN + blockIdx.x * 800) * CD);
  for (int i = tid; i < 6400; i += 256) {
    float4 v = b4[i];
    int c0 = (4 * i) & 31;
    v.x = __expf(v.x) * inv[c0];
    v.y = __expf(v.y) * inv[c0 + 1];
    v.z = __expf(v.z) * inv[c0 + 2];
    v.w = __expf(v.w) * inv[c0 + 3];
    b4[i] = v;
  }
}

// ---------------- launch ----------------

extern "C" void kernel_launch(void* const* d_in, const int* in_sizes, int n_in,
                              void* d_out, int out_size, void* d_ws, size_t ws_size,
                              hipStream_t stream) {
  const float* x   = (const float*)d_in[0];
  const float* W1  = (const float*)d_in[1];
  const float* as1 = (const float*)d_in[2];
  const float* ad1 = (const float*)d_in[3];
  const float* b1  = (const float*)d_in[4];
  const float* W2  = (const float*)d_in[5];
  const float* as2 = (const float*)d_in[6];
  const float* ad2 = (const float*)d_in[7];
  const float* b2  = (const float*)d_in[8];
  const float* wih = (const float*)d_in[9];
  const float* whh = (const float*)d_in[10];
  const float* bih = (const float*)d_in[11];
  const float* bhh = (const float*)d_in[12];
  const int*   ei  = (const int*)d_in[13];
  const int* srcp = ei;
  const int* dstp = ei + NE;
  float* out = (float*)d_out;

  float* ws = (float*)d_ws;
  float* al1s  = ws;  ws += (size_t)TT * NN * 8;
  float* al1d  = ws;  ws += (size_t)TT * NN * 8;
  float* h2    = ws;  ws += (size_t)TT * NN * CD;
  float* al2s  = ws;  ws += (size_t)TT * NN;
  float* al2d  = ws;  ws += (size_t)TT * NN;
  float* agg2o = ws;  ws += (size_t)TT * NN * CD;
  float* sums  = ws;  ws += TT * CD;
  float* wsrc  = ws;  ws += 256;
  float* wdst  = ws;  ws += 256;
  float* W1T   = ws;  ws += D1 * 32;
  float* W2T   = ws;  ws += 32 * D1;
  int* rowptr = (int*)ws;
  int* fill   = rowptr + NN + 1;
  int* csr    = fill + NN;
  int* deg    = csr + NE;

  hipMemsetAsync(sums, 0, TT * CD * sizeof(float), stream);
  hipMemsetAsync(deg, 0, NN * sizeof(int), stream);

  k_deg<<<(NE + 255) / 256, 256, 0, stream>>>(dstp, deg);
  k_scan<<<1, 1024, 0, stream>>>(deg, rowptr, fill);
  k_fill<<<(NE + 255) / 256, 256, 0, stream>>>(srcp, dstp, fill, csr);
  k_prew<<<1, 256, 0, stream>>>(W1, as1, ad1, W2, wsrc, wdst, W1T, W2T);

  k_logits8<<<(NN / 32) * TT, 256, 0, stream>>>(x, wsrc, wdst, al1s, al1d);
  k_fused8<<<PG1, 256, 0, stream>>>(x, W1T, b1, W2T, as2, ad2,
                                    al1s, al1d, rowptr, csr, h2, al2s, al2d);
  k_agg2_8<<<PG2, 256, 0, stream>>>(h2, al2s, al2d, rowptr, csr, b2, agg2o);
  k_lstm_all<<<NN / 16, 256, 0, stream>>>(agg2o, wih, whh, bih, bhh, out);

  k_sm_sum<<<dim3(25, TT), 256, 0, stream>>>(out, sums);
  k_sm_scale<<<dim3(25, TT), 256, 0, stream>>>(out, sums);
}